// Round 1
// baseline (284.875 us; speedup 1.0000x reference)
//
#include <hip/hip_runtime.h>
#include <hip/hip_bf16.h>

// FlippedQuanv3x3: reduces to 3x3 conv (C=16 -> O=64, pad=1, stride=1) with
// transformed weight Weff[o,c,k] = 0.25*(sum_i w[o,c,i]*A[i,k] + t0[k]),
// A[i,k] = Re Tr[P_i O_k], O_k = (E_rc + E_cr)/2 with (r,c) = divmod(k,4).
// x: [32,16,128,128] f32, weight: [64,16,15] f32, bias: [64,1] f32.
// out: [32,64,128,128] f32.

// ---- Pauli feature constants, computed on device (mirrors reference) ----
__device__ __forceinline__ void pauli_entry(int s, int r, int c, float& re, float& im) {
    // s: 0=I, 1=X, 2=Y, 3=Z (2x2)
    re = 0.f; im = 0.f;
    if (s == 0)      { if (r == c) re = 1.f; }
    else if (s == 1) { if (r != c) re = 1.f; }
    else if (s == 2) { if (r == 0 && c == 1) im = -1.f; else if (r == 1 && c == 0) im = 1.f; }
    else             { if (r == c) re = (r == 0) ? 1.f : -1.f; }
}

__device__ __forceinline__ float A_entry(int i, int k) {
    // pauli i = kron(S[(i+1)/4], S[(i+1)%4]); kron(A,B)[r,c]=A[r/2,c/2]*B[r%2,c%2]
    int j = i + 1, sa = j >> 2, sb = j & 3;
    int r = k >> 2, c = k & 3;
    float ar, ai, br, bi;
    pauli_entry(sa, r >> 1, c >> 1, ar, ai);
    pauli_entry(sb, r & 1, c & 1, br, bi);
    float re1 = ar * br - ai * bi;              // Re P[r][c]
    pauli_entry(sa, c >> 1, r >> 1, ar, ai);
    pauli_entry(sb, c & 1, r & 1, br, bi);
    float re2 = ar * br - ai * bi;              // Re P[c][r]
    return 0.5f * (re1 + re2);
}

// weff layout in ws: [c][k][o] (c*9+k major, 64 o minor), 16*9*64 = 9216 floats
__global__ __launch_bounds__(256) void weff_kernel(const float* __restrict__ weight,
                                                   float* __restrict__ weff) {
    int t = blockIdx.x * 256 + threadIdx.x;
    if (t >= 16 * 9 * 64) return;
    int o  = t & 63;
    int ck = t >> 6;
    int k  = ck % 9;
    int c  = ck / 9;
    float acc = (k == 0 || k == 5) ? 1.0f : 0.0f;   // t0[k]
    const float* w = weight + (o * 16 + c) * 15;
    #pragma unroll
    for (int i = 0; i < 15; ++i) acc += w[i] * A_entry(i, k);
    weff[t] = 0.25f * acc;
}

// Block: (b, 2 output rows, 128 w, 32 out-channels). 256 threads.
// thread: wg = tid&15 (8 w each), og = (tid>>4)&7 (4 o each), r = tid>>7 (row).
__global__ __launch_bounds__(256) void conv_kernel(const float* __restrict__ x,
                                                   const float* __restrict__ weff,
                                                   const float* __restrict__ bias,
                                                   float* __restrict__ out) {
    __shared__ float sx[16][4][132];   // [c][row -1..+2][w index 0..129 -> x w-1..128]
    __shared__ float sw[16][9][32];    // [c][k][o_local]

    const int tid  = threadIdx.x;
    const int b    = blockIdx.z;
    const int og32 = blockIdx.y;       // which half of the 64 out-channels
    const int h0   = blockIdx.x * 2;

    // ---- stage input tile: 16c x 4 rows x 128 interior floats, float4 global loads
    const float* xb = x + (size_t)b * 16 * 128 * 128;
    #pragma unroll
    for (int j = 0; j < 8; ++j) {
        int vid = tid + j * 256;       // < 2048 float4s
        int c   = vid >> 7;
        int rem = vid & 127;
        int rr  = rem >> 5;
        int v   = rem & 31;
        int h   = h0 - 1 + rr;
        float4 val = make_float4(0.f, 0.f, 0.f, 0.f);
        if (h >= 0 && h < 128)
            val = *(const float4*)(xb + ((c * 128 + h) * 128 + v * 4));
        sx[c][rr][1 + v * 4 + 0] = val.x;
        sx[c][rr][1 + v * 4 + 1] = val.y;
        sx[c][rr][1 + v * 4 + 2] = val.z;
        sx[c][rr][1 + v * 4 + 3] = val.w;
    }
    if (tid < 128) {                   // w halo (always zero pad at w=-1, w=128)
        int c = tid >> 3, rr = (tid >> 1) & 3, side = tid & 1;
        sx[c][rr][side ? 129 : 0] = 0.f;
    }
    // ---- stage weights for this 32-channel group
    #pragma unroll
    for (int j = 0; j < 18; ++j) {
        int idx = tid + j * 256;       // < 4608
        int ol  = idx & 31;
        int ck  = idx >> 5;
        ((float*)sw)[idx] = weff[ck * 64 + og32 * 32 + ol];
    }
    __syncthreads();

    const int wg = tid & 15;
    const int og = (tid >> 4) & 7;
    const int r  = tid >> 7;
    const int w0 = wg * 8;

    float acc[4][8];
    #pragma unroll
    for (int oo = 0; oo < 4; ++oo)
        #pragma unroll
        for (int ww = 0; ww < 8; ++ww) acc[oo][ww] = 0.f;

    #pragma unroll 1
    for (int c = 0; c < 16; ++c) {
        #pragma unroll
        for (int kh = 0; kh < 3; ++kh) {
            const float* src = &sx[c][r + kh][w0];
            float4 p0 = *(const float4*)(src);
            float4 p1 = *(const float4*)(src + 4);
            float2 p2 = *(const float2*)(src + 8);
            float p[10] = {p0.x, p0.y, p0.z, p0.w, p1.x, p1.y, p1.z, p1.w, p2.x, p2.y};
            #pragma unroll
            for (int kw = 0; kw < 3; ++kw) {
                float4 wv = *(const float4*)&sw[c][kh * 3 + kw][og * 4];
                float wf[4] = {wv.x, wv.y, wv.z, wv.w};
                #pragma unroll
                for (int oo = 0; oo < 4; ++oo)
                    #pragma unroll
                    for (int ww = 0; ww < 8; ++ww)
                        acc[oo][ww] = fmaf(wf[oo], p[ww + kw], acc[oo][ww]);
            }
        }
    }

    const int h = h0 + r;
    #pragma unroll
    for (int oo = 0; oo < 4; ++oo) {
        int o = og32 * 32 + og * 4 + oo;
        float bv = bias[o];
        float* dst = out + (((size_t)b * 64 + o) * 128 + h) * 128 + w0;
        float4 v0 = make_float4(acc[oo][0] + bv, acc[oo][1] + bv,
                                acc[oo][2] + bv, acc[oo][3] + bv);
        float4 v1 = make_float4(acc[oo][4] + bv, acc[oo][5] + bv,
                                acc[oo][6] + bv, acc[oo][7] + bv);
        *(float4*)dst       = v0;
        *(float4*)(dst + 4) = v1;
    }
}

extern "C" void kernel_launch(void* const* d_in, const int* in_sizes, int n_in,
                              void* d_out, int out_size, void* d_ws, size_t ws_size,
                              hipStream_t stream) {
    const float* x      = (const float*)d_in[0];   // [32,16,128,128]
    const float* weight = (const float*)d_in[1];   // [64,16,15]
    const float* bias   = (const float*)d_in[2];   // [64,1]
    float* out  = (float*)d_out;                   // [32,64,128,128]
    float* weff = (float*)d_ws;                    // 9216 floats

    weff_kernel<<<36, 256, 0, stream>>>(weight, weff);
    dim3 grid(64, 2, 32);   // h-tiles(2 rows) x out-channel-halves x batch
    conv_kernel<<<grid, 256, 0, stream>>>(x, weff, bias, out);
}

// Round 2
// 196.126 us; speedup vs baseline: 1.4525x; 1.4525x over previous
//
#include <hip/hip_runtime.h>
#include <hip/hip_bf16.h>

// FlippedQuanv3x3 == 3x3 conv (C=16 -> O=64, pad=1) with transformed weight
// Weff[o,c,k9] = 0.25*(sum_i w[o,c,i]*A[i,k9] + t0[k9]).
// Implemented as implicit GEMM on bf16 MFMA: D[o, n=(b,h,w)] = Weff x im2col(x).
// K = 16c*9 = 144, padded to 160 = 5 chunks of 16x16x32.
// Prep kernel packs Weff into exact A-fragment order (bf16) in d_ws.

typedef short bf16x8 __attribute__((ext_vector_type(8)));   // 8 bf16 = 4 VGPR
typedef float f32x4 __attribute__((ext_vector_type(4)));

// ---- Pauli feature constants (verified in R1) ----
__device__ __forceinline__ void pauli_entry(int s, int r, int c, float& re, float& im) {
    re = 0.f; im = 0.f;
    if (s == 0)      { if (r == c) re = 1.f; }
    else if (s == 1) { if (r != c) re = 1.f; }
    else if (s == 2) { if (r == 0 && c == 1) im = -1.f; else if (r == 1 && c == 0) im = 1.f; }
    else             { if (r == c) re = (r == 0) ? 1.f : -1.f; }
}

__device__ __forceinline__ float A_entry(int i, int k) {
    int j = i + 1, sa = j >> 2, sb = j & 3;
    int r = k >> 2, c = k & 3;
    float ar, ai, br, bi;
    pauli_entry(sa, r >> 1, c >> 1, ar, ai);
    pauli_entry(sb, r & 1, c & 1, br, bi);
    float re1 = ar * br - ai * bi;
    pauli_entry(sa, c >> 1, r >> 1, ar, ai);
    pauli_entry(sb, c & 1, r & 1, br, bi);
    float re2 = ar * br - ai * bi;
    return 0.5f * (re1 + re2);
}

__device__ __forceinline__ short f2bf(float f) {   // RNE float->bf16 bits
    union { float f; unsigned int u; } a; a.f = f;
    unsigned int r = a.u + 0x7fffu + ((a.u >> 16) & 1u);
    return (short)(r >> 16);
}

// ---- prep: Weff in A-fragment order: afrag[(ch*4+mt)*64 + lane][j=0..7] bf16
// A-operand layout (m89/m118): A[m = lane&15][k = (lane>>4)*8 + j], m = mt*16+(lane&15),
// k_global = ch*32 + (lane>>4)*8 + j; zero for k >= 144.
__global__ __launch_bounds__(256) void prep_kernel(const float* __restrict__ weight,
                                                   short* __restrict__ afrag) {
    int t = blockIdx.x * 256 + threadIdx.x;
    if (t >= 1280) return;
    int lane = t & 63;
    int mt   = (t >> 6) & 3;
    int ch   = t >> 8;
    int quad = lane >> 4;
    int m    = mt * 16 + (lane & 15);
    short vals[8];
    #pragma unroll
    for (int j = 0; j < 8; ++j) {
        int k = ch * 32 + quad * 8 + j;
        float v = 0.f;
        if (k < 144) {
            int c  = k / 9;
            int k9 = k - 9 * c;
            float acc = (k9 == 0 || k9 == 5) ? 1.f : 0.f;   // t0
            const float* w = weight + (m * 16 + c) * 15;
            #pragma unroll
            for (int i = 0; i < 15; ++i) acc += w[i] * A_entry(i, k9);
            v = 0.25f * acc;
        }
        vals[j] = f2bf(v);
    }
    *(bf16x8*)(afrag + t * 8) = *(bf16x8*)vals;
}

// ---- main: one block per (b, h). 256 thr = 4 waves; wave -> 32 pixels x 64 o.
__global__ __launch_bounds__(256) void conv_mfma(const float* __restrict__ x,
                                                 const short* __restrict__ afrag,
                                                 const float* __restrict__ bias,
                                                 float* __restrict__ out) {
    __shared__ float sx[48 * 136];      // [row=(c*3+kh)][4 zpad | 128 interior | 4 zpad]
    __shared__ short sa[1280 * 8];      // A fragments, frag-linear

    const int tid = threadIdx.x;
    const int h   = blockIdx.x;
    const int b   = blockIdx.y;

    // stage A fragments (coalesced 16B)
    #pragma unroll
    for (int j = 0; j < 5; ++j) {
        int vid = tid + j * 256;
        *(bf16x8*)(sa + vid * 8) = *(const bf16x8*)(afrag + vid * 8);
    }
    // stage x rows h-1..h+1, all 16 channels
    const float* xb = x + (size_t)b * 16 * 128 * 128;
    #pragma unroll
    for (int j = 0; j < 6; ++j) {
        int vid = tid + j * 256;        // < 1536 float4s
        int row = vid >> 5;             // c*3 + kh, < 48
        int v   = vid & 31;
        int c   = row / 3;
        int kh  = row - 3 * c;
        int hp  = h - 1 + kh;
        float4 val = make_float4(0.f, 0.f, 0.f, 0.f);
        if (hp >= 0 && hp < 128)
            val = *(const float4*)(xb + (c * 128 + hp) * 128 + v * 4);
        *(float4*)(sx + row * 136 + 4 + v * 4) = val;
    }
    if (tid < 48) {                      // halo zeros (w=-1 at idx 3, w=128.. at 132)
        *(float4*)(sx + tid * 136)       = make_float4(0.f, 0.f, 0.f, 0.f);
        *(float4*)(sx + tid * 136 + 132) = make_float4(0.f, 0.f, 0.f, 0.f);
    }
    __syncthreads();

    const int lane  = tid & 63;
    const int wave  = tid >> 6;
    const int quad  = lane >> 4;
    const int nlo   = lane & 15;
    const int wbase = wave * 32 + nlo;   // pixel col for n-tile 0; +16 for n-tile 1

    f32x4 acc[2][4] = {};

    #pragma unroll
    for (int ch = 0; ch < 5; ++ch) {
        float b0[8], b1[8];
        #pragma unroll
        for (int j = 0; j < 8; ++j) {
            int k  = ch * 32 + quad * 8 + j;
            int kc = (k < 144) ? k : 0;          // pad lanes read row 0 (A=0 there)
            int c  = kc / 9;
            int r9 = kc - 9 * c;
            int kh = r9 / 3;
            int kw = r9 - 3 * kh;
            const float* p = sx + (c * 3 + kh) * 136 + 3 + kw + wbase;
            b0[j] = p[0];
            b1[j] = p[16];
        }
        bf16x8 bf0, bf1;
        #pragma unroll
        for (int j = 0; j < 8; ++j) { bf0[j] = f2bf(b0[j]); bf1[j] = f2bf(b1[j]); }
        #pragma unroll
        for (int mt = 0; mt < 4; ++mt) {
            bf16x8 af = *(const bf16x8*)(sa + ((ch * 4 + mt) * 64 + lane) * 8);
            acc[0][mt] = __builtin_amdgcn_mfma_f32_16x16x32_bf16(af, bf0, acc[0][mt], 0, 0, 0);
            acc[1][mt] = __builtin_amdgcn_mfma_f32_16x16x32_bf16(af, bf1, acc[1][mt], 0, 0, 0);
        }
    }

    // epilogue: D[row=quad*4+reg (o within mtile), col=nlo (pixel)]
    #pragma unroll
    for (int mt = 0; mt < 4; ++mt) {
        f32x4 bv = *(const f32x4*)(bias + mt * 16 + quad * 4);
        float* dst = out + (((size_t)b * 64 + mt * 16 + quad * 4) * 128 + h) * 128;
        #pragma unroll
        for (int reg = 0; reg < 4; ++reg) {
            float* d = dst + (size_t)reg * 128 * 128;
            d[wbase]      = acc[0][mt][reg] + bv[reg];
            d[wbase + 16] = acc[1][mt][reg] + bv[reg];
        }
    }
}

extern "C" void kernel_launch(void* const* d_in, const int* in_sizes, int n_in,
                              void* d_out, int out_size, void* d_ws, size_t ws_size,
                              hipStream_t stream) {
    const float* x      = (const float*)d_in[0];   // [32,16,128,128]
    const float* weight = (const float*)d_in[1];   // [64,16,15]
    const float* bias   = (const float*)d_in[2];   // [64,1]
    float* out   = (float*)d_out;                  // [32,64,128,128]
    short* afrag = (short*)d_ws;                   // 1280*8 bf16 = 20 KB

    prep_kernel<<<5, 256, 0, stream>>>(weight, afrag);
    dim3 grid(128, 32);                            // (h, b)
    conv_mfma<<<grid, 256, 0, stream>>>(x, afrag, bias, out);
}

// Round 3
// 174.631 us; speedup vs baseline: 1.6313x; 1.1231x over previous
//
#include <hip/hip_runtime.h>
#include <hip/hip_bf16.h>

// FlippedQuanv3x3 == 3x3 conv (C=16 -> O=64, pad=1) with transformed weight
// Weff[o,c,k9] = 0.25*(sum_i w[o,c,i]*A[i,k9] + t0[k9]).
// Implicit GEMM on bf16 MFMA: D[o, n=(b,h,w)] = Weff x im2col(x).
// K = 144 padded to 160 = 5 chunks of 16x16x32. A-frags held in registers.
// Block = (b, 4 output rows); wave w owns row h0+w; 4 npair-iters of 32 px.

typedef short bf16x8 __attribute__((ext_vector_type(8)));   // 8 bf16 = 4 VGPR
typedef float f32x4 __attribute__((ext_vector_type(4)));

// ---- Pauli feature constants (verified R1/R2) ----
__device__ __forceinline__ void pauli_entry(int s, int r, int c, float& re, float& im) {
    re = 0.f; im = 0.f;
    if (s == 0)      { if (r == c) re = 1.f; }
    else if (s == 1) { if (r != c) re = 1.f; }
    else if (s == 2) { if (r == 0 && c == 1) im = -1.f; else if (r == 1 && c == 0) im = 1.f; }
    else             { if (r == c) re = (r == 0) ? 1.f : -1.f; }
}

__device__ __forceinline__ float A_entry(int i, int k) {
    int j = i + 1, sa = j >> 2, sb = j & 3;
    int r = k >> 2, c = k & 3;
    float ar, ai, br, bi;
    pauli_entry(sa, r >> 1, c >> 1, ar, ai);
    pauli_entry(sb, r & 1, c & 1, br, bi);
    float re1 = ar * br - ai * bi;
    pauli_entry(sa, c >> 1, r >> 1, ar, ai);
    pauli_entry(sb, c & 1, r & 1, br, bi);
    float re2 = ar * br - ai * bi;
    return 0.5f * (re1 + re2);
}

__device__ __forceinline__ short f2bf(float f) {   // RNE float->bf16 bits
    union { float f; unsigned int u; } a; a.f = f;
    unsigned int r = a.u + 0x7fffu + ((a.u >> 16) & 1u);
    return (short)(r >> 16);
}

// pack two floats -> two bf16 (RNE) in one u32 (lo = a, hi = b)
__device__ __forceinline__ unsigned pk_bf16(float a, float b) {
#if __has_builtin(__builtin_amdgcn_cvt_pk_bf16_f32)
    typedef __bf16 bf2 __attribute__((ext_vector_type(2)));
    bf2 r = __builtin_amdgcn_cvt_pk_bf16_f32(a, b);
    union { bf2 v; unsigned u; } cv; cv.v = r;
    return cv.u;
#else
    union { float f; unsigned u; } x, y; x.f = a; y.f = b;
    unsigned ra = x.u + 0x7fffu + ((x.u >> 16) & 1u);
    unsigned rb = y.u + 0x7fffu + ((y.u >> 16) & 1u);
    return (ra >> 16) | (rb & 0xffff0000u);
#endif
}

// ---- prep: Weff in A-fragment order: afrag[(ch*4+mt)*64 + lane][j=0..7] bf16
// A[m = lane&15][k = (lane>>4)*8 + j], m = mt*16+(lane&15), k = ch*32+..; 0 for k>=144.
__global__ __launch_bounds__(256) void prep_kernel(const float* __restrict__ weight,
                                                   short* __restrict__ afrag) {
    int t = blockIdx.x * 256 + threadIdx.x;
    if (t >= 1280) return;
    int lane = t & 63;
    int mt   = (t >> 6) & 3;
    int ch   = t >> 8;
    int quad = lane >> 4;
    int m    = mt * 16 + (lane & 15);
    short vals[8];
    #pragma unroll
    for (int j = 0; j < 8; ++j) {
        int k = ch * 32 + quad * 8 + j;
        float v = 0.f;
        if (k < 144) {
            int c  = k / 9;
            int k9 = k - 9 * c;
            float acc = (k9 == 0 || k9 == 5) ? 1.f : 0.f;   // t0
            const float* w = weight + (m * 16 + c) * 15;
            #pragma unroll
            for (int i = 0; i < 15; ++i) acc += w[i] * A_entry(i, k9);
            v = 0.25f * acc;
        }
        vals[j] = f2bf(v);
    }
    *(bf16x8*)(afrag + t * 8) = *(bf16x8*)vals;
}

// ---- main: block = (b, 4 output rows h0..h0+3). 256 thr / 4 waves.
// Wave w computes row h0+w: 64 o x 128 px, as 4 npair-iters of (2 n-tiles x 4 m-tiles).
__global__ __launch_bounds__(256) void conv_mfma(const float* __restrict__ x,
                                                 const short* __restrict__ afrag,
                                                 const float* __restrict__ bias,
                                                 float* __restrict__ out) {
    __shared__ float sx[16 * 6 * 136];   // [c][row h0-1..h0+4][4 zpad |128| 4 zpad]

    const int tid  = threadIdx.x;
    const int h0   = blockIdx.x * 4;
    const int b    = blockIdx.y;
    const int lane = tid & 63;
    const int wave = tid >> 6;
    const int quad = lane >> 4;
    const int nlo  = lane & 15;

    // ---- A fragments into registers (global, L2-broadcast), issued first
    bf16x8 Areg[20];
    #pragma unroll
    for (int i = 0; i < 20; ++i)
        Areg[i] = *(const bf16x8*)(afrag + (i * 64 + lane) * 8);

    // ---- stage x rows h0-1 .. h0+4, all 16 channels, float4 loads
    const float* xb = x + (size_t)b * 16 * 128 * 128;
    #pragma unroll
    for (int j = 0; j < 12; ++j) {
        int vid = tid + j * 256;         // < 3072 float4s
        int row = vid >> 5;              // c*6 + r, < 96
        int v   = vid & 31;
        int c   = row / 6;
        int r   = row - 6 * c;
        int hp  = h0 - 1 + r;
        float4 val = make_float4(0.f, 0.f, 0.f, 0.f);
        if (hp >= 0 && hp < 128)
            val = *(const float4*)(xb + (c * 128 + hp) * 128 + v * 4);
        *(float4*)(sx + row * 136 + 4 + v * 4) = val;
    }
    if (tid < 192) {                     // halo zeros
        int row = tid >> 1, side = tid & 1;
        *(float4*)(sx + row * 136 + (side ? 132 : 0)) = make_float4(0.f, 0.f, 0.f, 0.f);
    }

    // ---- per-lane gather offsets (dwords into sx), packed 2-per-VGPR
    unsigned offp[20];
    #pragma unroll
    for (int ch = 0; ch < 5; ++ch) {
        #pragma unroll
        for (int j2 = 0; j2 < 4; ++j2) {
            unsigned o01[2];
            #pragma unroll
            for (int t = 0; t < 2; ++t) {
                int k = ch * 32 + quad * 8 + j2 * 2 + t;
                if (k >= 144) k = 0;     // pad lanes: A=0, any valid addr
                int c  = k / 9, r9 = k - 9 * c;
                int kh = r9 / 3, kw = r9 - 3 * kh;
                o01[t] = (unsigned)((c * 6 + wave + kh) * 136 + 3 + kw + nlo);
            }
            offp[ch * 4 + j2] = o01[0] | (o01[1] << 16);
        }
    }
    __syncthreads();

    const int h = h0 + wave;
    #pragma unroll
    for (int np = 0; np < 4; ++np) {
        const int pixadd = np * 32;

        // init acc with bias: acc[nt][mt][reg] -> o = mt*16 + quad*4 + reg
        f32x4 acc[2][4];
        #pragma unroll
        for (int mt = 0; mt < 4; ++mt) {
            f32x4 bv = *(const f32x4*)(bias + mt * 16 + quad * 4);
            acc[0][mt] = bv;
            acc[1][mt] = bv;
        }

        #pragma unroll
        for (int ch = 0; ch < 5; ++ch) {
            unsigned b0p[4], b1p[4];
            #pragma unroll
            for (int j2 = 0; j2 < 4; ++j2) {
                unsigned pk = offp[ch * 4 + j2];
                const float* p0 = sx + (pk & 0xffffu) + pixadd;
                const float* p1 = sx + (pk >> 16) + pixadd;
                float a0 = p0[0], a1 = p0[16];   // ds_read2_b32 offset0:0 offset1:16
                float c0 = p1[0], c1 = p1[16];
                b0p[j2] = pk_bf16(a0, c0);       // pixel-tile 0: k=2j2, 2j2+1
                b1p[j2] = pk_bf16(a1, c1);       // pixel-tile 1
            }
            union { unsigned u[4]; bf16x8 v; } B0, B1;
            #pragma unroll
            for (int j2 = 0; j2 < 4; ++j2) { B0.u[j2] = b0p[j2]; B1.u[j2] = b1p[j2]; }
            #pragma unroll
            for (int mt = 0; mt < 4; ++mt) {
                acc[0][mt] = __builtin_amdgcn_mfma_f32_16x16x32_bf16(Areg[ch * 4 + mt], B0.v, acc[0][mt], 0, 0, 0);
                acc[1][mt] = __builtin_amdgcn_mfma_f32_16x16x32_bf16(Areg[ch * 4 + mt], B1.v, acc[1][mt], 0, 0, 0);
            }
        }

        // epilogue: D[row = quad*4+reg (o), col = nlo (pixel)]
        const int wp = pixadd + nlo;
        #pragma unroll
        for (int mt = 0; mt < 4; ++mt) {
            float* dst = out + (((size_t)b * 64 + mt * 16 + quad * 4) * 128 + h) * 128;
            #pragma unroll
            for (int reg = 0; reg < 4; ++reg) {
                float* d = dst + (size_t)reg * 128 * 128;
                d[wp]      = acc[0][mt][reg];
                d[wp + 16] = acc[1][mt][reg];
            }
        }
    }
}

extern "C" void kernel_launch(void* const* d_in, const int* in_sizes, int n_in,
                              void* d_out, int out_size, void* d_ws, size_t ws_size,
                              hipStream_t stream) {
    const float* x      = (const float*)d_in[0];   // [32,16,128,128]
    const float* weight = (const float*)d_in[1];   // [64,16,15]
    const float* bias   = (const float*)d_in[2];   // [64,1]
    float* out   = (float*)d_out;                  // [32,64,128,128]
    short* afrag = (short*)d_ws;                   // 1280*8 bf16 = 20 KB

    prep_kernel<<<5, 256, 0, stream>>>(weight, afrag);
    dim3 grid(32, 32);                             // (h-tiles of 4 rows, b)
    conv_mfma<<<grid, 256, 0, stream>>>(x, afrag, bias, out);
}

// Round 4
// 171.452 us; speedup vs baseline: 1.6615x; 1.0185x over previous
//
#include <hip/hip_runtime.h>
#include <hip/hip_bf16.h>

// FlippedQuanv3x3 == 3x3 conv (C=16 -> O=64, pad=1) with transformed weight
// Weff[o,c,k9] = 0.25*(sum_i w[o,c,i]*A[i,k9] + t0[k9]).
// Implicit GEMM, bf16 MFMA 16x16x32. K order = tap-major: k = tap*16 + c
// (tap = 3x3 patch index 0..8, c = channel). K = 144 padded to 160 = 5 chunks.
// Operand roles: A = im2col(x) (M = pixels), B = Weff (N = o). Lane's A-frag
// (8 k = 8 consecutive c) = ONE ds_read_b128 from a c-fastest bf16 LDS tile.
// D rows = pixels -> each lane stores 4 consecutive pixels (dwordx4).
// Block = (b, 8 output rows); grid 16x32 = 512 = exactly 2 blocks/CU.

typedef short bf16x8 __attribute__((ext_vector_type(8)));   // 8 bf16 = 4 VGPR
typedef float f32x4 __attribute__((ext_vector_type(4)));

// ---- Pauli feature constants (verified R1-R3) ----
__device__ __forceinline__ void pauli_entry(int s, int r, int c, float& re, float& im) {
    re = 0.f; im = 0.f;
    if (s == 0)      { if (r == c) re = 1.f; }
    else if (s == 1) { if (r != c) re = 1.f; }
    else if (s == 2) { if (r == 0 && c == 1) im = -1.f; else if (r == 1 && c == 0) im = 1.f; }
    else             { if (r == c) re = (r == 0) ? 1.f : -1.f; }
}

__device__ __forceinline__ float A_entry(int i, int k) {
    int j = i + 1, sa = j >> 2, sb = j & 3;
    int r = k >> 2, c = k & 3;        // 4x4 flat embedding (M.flat[k]) — verified R1
    float ar, ai, br, bi;
    pauli_entry(sa, r >> 1, c >> 1, ar, ai);
    pauli_entry(sb, r & 1, c & 1, br, bi);
    float re1 = ar * br - ai * bi;
    pauli_entry(sa, c >> 1, r >> 1, ar, ai);
    pauli_entry(sb, c & 1, r & 1, br, bi);
    float re2 = ar * br - ai * bi;
    return 0.5f * (re1 + re2);
}

__device__ __forceinline__ short f2bf(float f) {   // RNE float->bf16 bits
    union { float f; unsigned int u; } a; a.f = f;
    unsigned int r = a.u + 0x7fffu + ((a.u >> 16) & 1u);
    return (short)(r >> 16);
}

// pack two floats -> two bf16 (RNE) in one u32 (lo = a, hi = b)
__device__ __forceinline__ unsigned pk_bf16(float a, float b) {
#if __has_builtin(__builtin_amdgcn_cvt_pk_bf16_f32)
    typedef __bf16 bf2 __attribute__((ext_vector_type(2)));
    bf2 r = __builtin_amdgcn_cvt_pk_bf16_f32(a, b);
    union { bf2 v; unsigned u; } cv; cv.v = r;
    return cv.u;
#else
    union { float f; unsigned u; } x, y; x.f = a; y.f = b;
    unsigned ra = x.u + 0x7fffu + ((x.u >> 16) & 1u);
    unsigned rb = y.u + 0x7fffu + ((y.u >> 16) & 1u);
    return (ra >> 16) | (rb & 0xffff0000u);
#endif
}

// ---- prep: Weff as MFMA B-fragments, k tap-major.
// bfrag[(chunk*4 + ot)*64 + lane][j] = Weff[o = ot*16 + (lane&15)]
//   [gk = chunk*32 + (lane>>4)*8 + j], gk -> (tap = gk>>4, c = gk&15); 0 if gk>=144.
__global__ __launch_bounds__(256) void prep_kernel(const float* __restrict__ weight,
                                                   short* __restrict__ bfrag) {
    int t = blockIdx.x * 256 + threadIdx.x;
    if (t >= 1280) return;
    int lane  = t & 63;
    int ot    = (t >> 6) & 3;
    int chunk = t >> 8;
    int q     = lane >> 4;
    int o     = ot * 16 + (lane & 15);
    short vals[8];
    #pragma unroll
    for (int j = 0; j < 8; ++j) {
        int gk = chunk * 32 + q * 8 + j;
        float v = 0.f;
        if (gk < 144) {
            int tap = gk >> 4;         // patch index 0..8
            int c   = gk & 15;         // channel
            float acc = (tap == 0 || tap == 5) ? 1.f : 0.f;   // t0
            const float* w = weight + (o * 16 + c) * 15;
            #pragma unroll
            for (int i = 0; i < 15; ++i) acc += w[i] * A_entry(i, tap);
            v = 0.25f * acc;
        }
        vals[j] = f2bf(v);
    }
    *(bf16x8*)(bfrag + t * 8) = *(bf16x8*)vals;
}

// LDS element index: el(row, w, c) = (row*136 + w)*16 + slot*8 + (c&7),
// slot = (c>>3) ^ ((w>>2)&1). row in [0,10) = x rows h0-1..h0+8; w in [0,136)
// = x w -4..131. 136*16 el/row => row stride 4352 B == 0 mod 32 banks; the
// (w>>2) XOR keeps hot-loop b128 reads <=2-way conflicted (free, m136).
__global__ __launch_bounds__(256) void conv_mfma(const float* __restrict__ x,
                                                 const short* __restrict__ bfrag,
                                                 const float* __restrict__ bias,
                                                 float* __restrict__ out) {
    __shared__ short sx[10 * 136 * 16];   // 43520 B

    const int tid  = threadIdx.x;
    const int h0   = blockIdx.x * 8;
    const int b    = blockIdx.y;
    const int lane = tid & 63;
    const int wave = tid >> 6;
    const int q    = lane >> 4;
    const int nlo  = lane & 15;

    // ---- stage x -> bf16 c-fastest LDS tile. 2720 positions = (row,chalf,w).
    const float* xb = x + (size_t)b * 16 * 128 * 128;
    #pragma unroll
    for (int it = 0; it < 11; ++it) {
        int pos = tid + it * 256;
        if (pos < 2720) {
            int seg = pos / 136;           // row*2 + chalf
            int w   = pos - seg * 136;
            int row = seg >> 1, chalf = seg & 1;
            int hp  = h0 - 1 + row;
            int xw  = w - 4;
            bool ok = ((unsigned)hp < 128u) && ((unsigned)xw < 128u);
            const float* src = xb + (size_t)(chalf * 8) * 16384 + hp * 128 + xw;
            float v[8];
            #pragma unroll
            for (int j = 0; j < 8; ++j)
                v[j] = ok ? src[(size_t)j * 16384] : 0.f;
            int slot = (chalf ^ (w >> 2)) & 1;
            unsigned* dst = (unsigned*)sx + (row * 136 + w) * 8 + slot * 4;
            #pragma unroll
            for (int j2 = 0; j2 < 4; ++j2)
                dst[j2] = pk_bf16(v[2 * j2], v[2 * j2 + 1]);
        }
    }

    // ---- weights into registers (80 VGPR), bias per lane
    bf16x8 Breg[20];
    #pragma unroll
    for (int i = 0; i < 20; ++i)
        Breg[i] = *(const bf16x8*)(bfrag + (i * 64 + lane) * 8);
    float bv[4];
    #pragma unroll
    for (int ot = 0; ot < 4; ++ot) bv[ot] = bias[ot * 16 + nlo];

    // ---- per-chunk A-read base (np=0, mt=0, rowsel=0); rest are imm offsets
    int baseA[5];
    #pragma unroll
    for (int ch = 0; ch < 5; ++ch) {
        int tap = ch * 2 + (q >> 1);
        if (tap > 8) tap = 8;             // chunk 4 upper half: pad, B=0
        int kh = tap / 3, kw = tap - 3 * kh;
        int chalf = q & 1;
        int row0  = wave * 2 + kh;
        int w0    = nlo + kw + 3;         // LDS w-index for pixel nlo
        int slot  = (chalf ^ (w0 >> 2)) & 1;
        baseA[ch] = (row0 * 136 + w0) * 16 + slot * 8;
    }
    __syncthreads();

    // ---- hot loop: 2 rows x 4 pixel-groups; per phase 5 chunks x (2 rd + 8 mfma)
    #pragma unroll
    for (int rs = 0; rs < 2; ++rs) {
        const int h = h0 + wave * 2 + rs;
        #pragma unroll
        for (int np = 0; np < 4; ++np) {
            f32x4 acc[2][4];
            #pragma unroll
            for (int ot = 0; ot < 4; ++ot) {
                f32x4 ini = { bv[ot], bv[ot], bv[ot], bv[ot] };
                acc[0][ot] = ini;
                acc[1][ot] = ini;
            }
            #pragma unroll
            for (int ch = 0; ch < 5; ++ch) {
                const short* pA = sx + baseA[ch] + rs * 2176 + np * 512;
                bf16x8 A0 = *(const bf16x8*)(pA);        // m-tile 0 (pixels +0)
                bf16x8 A1 = *(const bf16x8*)(pA + 256);  // m-tile 1 (pixels +16)
                #pragma unroll
                for (int ot = 0; ot < 4; ++ot) {
                    acc[0][ot] = __builtin_amdgcn_mfma_f32_16x16x32_bf16(A0, Breg[ch * 4 + ot], acc[0][ot], 0, 0, 0);
                    acc[1][ot] = __builtin_amdgcn_mfma_f32_16x16x32_bf16(A1, Breg[ch * 4 + ot], acc[1][ot], 0, 0, 0);
                }
            }
            // D[m = q*4+reg (pixel), n = nlo (o)] -> dwordx4 per (mt, ot)
            #pragma unroll
            for (int ot = 0; ot < 4; ++ot) {
                float* dst = out + (((size_t)b * 64 + ot * 16 + nlo) * 128 + h) * 128
                           + np * 32 + q * 4;
                *(f32x4*)dst        = acc[0][ot];
                *(f32x4*)(dst + 16) = acc[1][ot];
            }
        }
    }
}

extern "C" void kernel_launch(void* const* d_in, const int* in_sizes, int n_in,
                              void* d_out, int out_size, void* d_ws, size_t ws_size,
                              hipStream_t stream) {
    const float* x      = (const float*)d_in[0];   // [32,16,128,128]
    const float* weight = (const float*)d_in[1];   // [64,16,15]
    const float* bias   = (const float*)d_in[2];   // [64,1]
    float* out   = (float*)d_out;                  // [32,64,128,128]
    short* bfrag = (short*)d_ws;                   // 1280*8 bf16 = 20 KB

    prep_kernel<<<5, 256, 0, stream>>>(weight, bfrag);
    dim3 grid(16, 32);                             // (h-tiles of 8 rows, b)
    conv_mfma<<<grid, 256, 0, stream>>>(x, bfrag, bias, out);
}